// Round 6
// baseline (195.001 us; speedup 1.0000x reference)
//
#include <hip/hip_runtime.h>
#include <hip/hip_bf16.h>
#include <math.h>

// ---------------------------------------------------------------------------
// LowRankSparseAttention on MI355X (gfx950)
//   1. prep (one kernel): cvt resid->A_bf, cvt W_V->Wt rows 2048+, virtual
//      K/V fills, transpose W_Q/W_K->Wt, transpose W_O->Wot
//   2. gemm1_fused (128x128 tiles): QKV proj, fused epilogue:
//        Q: +bQ, rotary, /sqrt(32) -> Qb bf16 [(b,h)][1024][32]   (dense)
//        K: +bK, rotary            -> Kb bf16 [(b,h)][1152][32]   (dense)
//        V: +bV, permuted transpose-> Vb bf16 [(b,h)][64][1152]
//   3. attn_mfma: flash attn, S^T/O^T form, 4-way split-K per 16-query tile
//      (waves each do <=5 chunks, LDS merge), XCD-swizzled grid -> Zb bf16
//   4. gemm2 (64x64 tiles): out[2048x1024] f32 = Zb @ Wot^T
// ---------------------------------------------------------------------------

typedef short bf16x8 __attribute__((ext_vector_type(8)));
typedef short short4v __attribute__((ext_vector_type(4)));
typedef float f32x4 __attribute__((ext_vector_type(4)));
typedef int int4v __attribute__((ext_vector_type(4)));
typedef __hip_bfloat16 bf16;

#define AS1(p) ((const __attribute__((address_space(1))) void*)(const void*)(p))
#define AS3(p) ((__attribute__((address_space(3))) void*)(void*)(p))

static constexpr float INV_SCALE = 0.17677669529663687f;  // 1/sqrt(32)

// fast RNE f32->bf16 (finite values only): 4 int ops
__device__ inline short rnd_bf16(float x) {
  unsigned u = __float_as_uint(x);
  return (short)((u + 0x7fffu + ((u >> 16) & 1u)) >> 16);
}

// pack two positive f32 -> one dword of bf16 pair (round half-up):
// low short = bf16(lo), high short = bf16(hi)
__device__ inline int pack_bf16_pair(float hi, float lo) {
  unsigned a = __float_as_uint(hi) + 0x8000u;
  unsigned b = __float_as_uint(lo) + 0x8000u;
  return (int)__builtin_amdgcn_perm(a, b, 0x07060302u);
}

// ---- merged preprocessing kernel ------------------------------------------
__global__ __launch_bounds__(256) void prep(
    const float* __restrict__ resid, const float* __restrict__ WV,
    const float* __restrict__ WQ, const float* __restrict__ WK,
    const float* __restrict__ WO, const float* __restrict__ vk,
    const float* __restrict__ vv,
    bf16* __restrict__ A_bf, bf16* __restrict__ Wt, bf16* __restrict__ Wot,
    bf16* __restrict__ Kb, bf16* __restrict__ Vb) {
  __shared__ float t[64][65];
  const int blk = blockIdx.x, tid = threadIdx.x;
  if (blk < 4096) {
    const float* src = (blk < 2048) ? resid : WV;
    short* dst = (short*)((blk < 2048) ? A_bf : (Wt + (size_t)2048 * 1024));
    int i = ((blk & 2047) * 256 + tid) * 4;
    float4 v = *(const float4*)(src + i);
    dst[i + 0] = rnd_bf16(v.x); dst[i + 1] = rnd_bf16(v.y);
    dst[i + 2] = rnd_bf16(v.z); dst[i + 3] = rnd_bf16(v.w);
  } else if (blk < 7168) {
    int idx = (blk - 4096) * 256 + tid;
    if (idx < 262144) {              // Kb virtual: toks 1024..1151 per (b,h)
      int b = idx >> 17, rem = idx & 131071;
      int j = rem >> 10, c = rem & 1023;     // c = h*32+d
      int h = c >> 5, d = c & 31;
      float v = (j < 16) ? vk[j * 1024 + c] : 0.f;
      Kb[(((size_t)(b * 32 + h)) * 1152 + 1024 + j) * 32 + d] = __float2bfloat16(v);
    } else {                         // Vb virtual positions 1024..1151
      int i2 = idx - 262144;
      int b = i2 >> 18, rem = i2 & 262143;
      int ch = rem >> 7, p = rem & 127;
      int pl = p & 31;
      int u = ((pl & 4) << 2) | ((pl & 24) >> 1) | (pl & 3);
      int tok = 1024 + (p & ~31) + u;
      float v = (tok < 1040) ? vv[(size_t)(tok - 1024) * 2048 + ch] : 0.f;
      int hv = ch >> 6, c = ch & 63;
      Vb[(((size_t)(b * 32 + hv)) * 64 + c) * 1152 + 1024 + p] = __float2bfloat16(v);
    }
  } else if (blk < 8192) {
    int i = blk - 7168;
    int mt = i & 15, h = (i >> 4) & 31, qk = i >> 9;
    const float* W = qk ? WK : WQ;
    const int m0 = mt * 64;
    for (int idx = tid; idx < 64 * 32; idx += 256) {
      int ii = idx >> 5, d = idx & 31;
      t[ii][d] = W[((size_t)h * 1024 + m0 + ii) * 32 + d];
    }
    __syncthreads();
    const int rowbase = qk * 1024 + h * 32;
    for (int idx = tid; idx < 32 * 64; idx += 256) {
      int d = idx >> 6, ii = idx & 63;
      Wt[(size_t)(rowbase + d) * 1024 + m0 + ii] = __float2bfloat16(t[ii][d]);
    }
  } else {
    int i = blk - 8192;
    int h0 = (i & 31) * 64, m0 = (i >> 5) * 64;
    for (int idx = tid; idx < 64 * 64; idx += 256) {
      int ii = idx >> 6, j = idx & 63;
      t[ii][j] = WO[(size_t)(h0 + ii) * 1024 + m0 + j];
    }
    __syncthreads();
    for (int idx = tid; idx < 64 * 64; idx += 256) {
      int ii = idx >> 6, j = idx & 63;
      Wot[(size_t)(m0 + ii) * 2048 + h0 + j] = __float2bfloat16(t[j][ii]);
    }
  }
}

// ---- GEMM1 + fused epilogue: 128(M) x 128(N) tiles, K=1024 ----------------
// C-frag: m = tileM+wm+i*16+rq*4+r, n = tileN+wn+j*16+col. Wave's 64 cols =
// two QK heads (j=0/1: head hA dims 0-15/16-31; j=2/3: head hA+1) or one V
// head (j*16+col = channel).
__global__ __launch_bounds__(256) void gemm1_fused(
    const bf16* __restrict__ A, const bf16* __restrict__ Bt,
    const float* __restrict__ bQ, const float* __restrict__ bK,
    const float* __restrict__ bV,
    bf16* __restrict__ Qb, bf16* __restrict__ Kb, bf16* __restrict__ Vb) {
  __shared__ __align__(16) short As[128 * 32];
  __shared__ __align__(16) short Bs[128 * 32];
  const int tileM = blockIdx.y * 128, tileN = blockIdx.x * 128;
  const int tid = threadIdx.x, wave = tid >> 6, lane = tid & 63;
  const int wm = (wave >> 1) * 64, wn = (wave & 1) * 64;
  const int mrow = lane & 15, kq = lane >> 4;
  f32x4 acc[4][4] = {};

  for (int k0 = 0; k0 < 1024; k0 += 32) {
#pragma unroll
    for (int i = 0; i < 2; i++) {
      int c = (wave * 2 + i) * 64 + lane;
      int row = c >> 2, ko = (c & 3) * 8;
      const short* ga = (const short*)A + (size_t)(tileM + row) * 1024 + k0 + ko;
      const short* gb = (const short*)Bt + (size_t)(tileN + row) * 1024 + k0 + ko;
      __builtin_amdgcn_global_load_lds(AS1(ga), AS3(&As[(wave * 2 + i) * 512]), 16, 0, 0);
      __builtin_amdgcn_global_load_lds(AS1(gb), AS3(&Bs[(wave * 2 + i) * 512]), 16, 0, 0);
    }
    __syncthreads();
    bf16x8 af[4], bfr[4];
#pragma unroll
    for (int t = 0; t < 4; t++) {
      af[t]  = *(const bf16x8*)&As[(wm + t * 16 + mrow) * 32 + kq * 8];
      bfr[t] = *(const bf16x8*)&Bs[(wn + t * 16 + mrow) * 32 + kq * 8];
    }
#pragma unroll
    for (int i = 0; i < 4; i++)
#pragma unroll
      for (int j = 0; j < 4; j++)
        acc[i][j] = __builtin_amdgcn_mfma_f32_16x16x32_bf16(af[i], bfr[j], acc[i][j], 0, 0, 0);
    __syncthreads();
  }

  const int col = lane & 15, rq = lane >> 4;
  if (tileN < 2048) {
    // ---- two QK heads per wave: bias + rotary (d = col) -------------------
    const int qk = tileN >> 10;
    const float* bias = qk ? bK : bQ;
    const int hA = ((tileN & 1023) + wn) >> 5;
    const float b0a = bias[hA * 32 + col],        b1a = bias[hA * 32 + col + 16];
    const float b0b = bias[(hA + 1) * 32 + col],  b1b = bias[(hA + 1) * 32 + col + 16];
    const float invf = exp2f(col * -0.8304820237218406f);  // -log2(10000)/16
#pragma unroll
    for (int i = 0; i < 4; i++)
#pragma unroll
      for (int r = 0; r < 4; r++) {
        int mg = tileM + wm + i * 16 + rq * 4 + r;
        int s = mg & 1023, bb = mg >> 10;
        float sv, cv;
        __sincosf((float)s * invf, &sv, &cv);
#pragma unroll
        for (int p = 0; p < 2; p++) {
          float x0 = acc[i][2 * p][r]     + (p ? b0b : b0a);
          float x1 = acc[i][2 * p + 1][r] + (p ? b1b : b1a);
          float y0 = x0 * cv - x1 * sv, y1 = x1 * cv + x0 * sv;
          int h = hA + p;
          if (qk == 0) {
            short* q = (short*)Qb + (((size_t)(bb * 32 + h)) * 1024 + s) * 32 + col;
            q[0]  = rnd_bf16(y0 * INV_SCALE);
            q[16] = rnd_bf16(y1 * INV_SCALE);
          } else {
            short* kp = (short*)Kb + (((size_t)(bb * 32 + h)) * 1152 + s) * 32 + col;
            kp[0]  = rnd_bf16(y0);
            kp[16] = rnd_bf16(y1);
          }
        }
      }
  } else {
    // ---- V head: bias + permuted transpose into Vb[ch][tok] ---------------
    const int hv = (tileN - 2048 + wn) >> 6;
#pragma unroll
    for (int i = 0; i < 4; i++)
#pragma unroll
      for (int j = 0; j < 4; j++) {
        int c = j * 16 + col;
        float bias = bV[hv * 64 + c];
        int m0 = tileM + wm + i * 16 + rq * 4;
        int s0 = m0 & 1023, bb = m0 >> 10;
        int u0 = s0 & 31;  // 4-aligned; permutation preserves low 2 bits
        int p0 = (u0 & 3) | ((u0 & 16) >> 2) | ((u0 & 8) << 1) | ((u0 & 4) << 1);
        short4v s4;
#pragma unroll
        for (int r = 0; r < 4; r++) s4[r] = rnd_bf16(acc[i][j][r] + bias);
        *(short4v*)((short*)Vb + (((size_t)(bb * 32 + hv)) * 64 + c) * 1152 + (s0 & ~31) + p0) = s4;
      }
  }
}

// ---- MFMA flash attention: 4-way split-K per 16-query tile ----------------
// Block = one tile (16 queries) of one (hq,b); the tile's <=17 64-key chunks
// are split evenly over the 4 waves (max 5 each). Each wave runs independent
// online softmax (S^T = K@Q^T, lane owns query col; packed S^T C/D regs ARE
// the PV B-frag via token-permuted V). Waves 1-3 publish (m,l,O) in LDS;
// wave 0 merges with a_w = exp(m_w - m*) and writes Zb. Fully-masked or
// empty partials die via exp(-1e30 - m*) = 0 (m* finite: wave0 owns chunk 0).
// XCD swizzle: flat&7 owns 8 (hq,b) pairs entirely.
__global__ __launch_bounds__(256) void attn_mfma(
    const bf16* __restrict__ Qb, const bf16* __restrict__ Kb,
    const bf16* __restrict__ Vb, bf16* __restrict__ Zb) {
  __shared__ float Ms[3][64], Ls[3][64], Os[3][16][64];
  const int flat = blockIdx.x;
  const int xcd = flat & 7, j = flat >> 3;
  const int hqb = xcd * 8 + (j & 7);
  const int x = j >> 3;                 // tile 0..63
  const int hq = hqb & 31, b = hqb >> 5;
  const int wave = threadIdx.x >> 6, lane = threadIdx.x & 63;
  const int col = lane & 15, quad = lane >> 4;
  const int qw = x * 16;

  const bf16x8 qf = *(const bf16x8*)((const short*)Qb +
      (((size_t)(b * 32 + hq)) * 1024 + qw + col) * 32 + quad * 8);
  const short* kbase = (const short*)Kb + ((size_t)(b * 32 + hq)) * 1152 * 32 + quad * 8;
  const short* vbase = (const short*)Vb + (((size_t)(b * 32 + hq)) * 64 + col) * 1152 + quad * 8;

  const int kend = (qw + 32 < 1040) ? qw + 32 : 1040;
  const int nch = (kend + 63) >> 6;
  const int cbase = nch >> 2, crmd = nch & 3;
  const int mych = cbase + (wave < crmd);
  const int cst = wave * cbase + ((wave < crmd) ? wave : crmd);

  f32x4 O[4] = {};
  float m = -1e30f, l = 0.f;

  for (int ci = 0; ci < mych; ci++) {
    const int kc = (cst + ci) * 64;
    // ---- S^T = K @ Q^T : lane holds S^T[key=kc+mbk*16+quad*4+r][q=qw+col]
    f32x4 St[4] = {};
#pragma unroll
    for (int mbk = 0; mbk < 4; mbk++) {
      bf16x8 kf = *(const bf16x8*)(kbase + (size_t)(kc + mbk * 16 + col) * 32);
      St[mbk] = __builtin_amdgcn_mfma_f32_16x16x32_bf16(kf, qf, St[mbk], 0, 0, 0);
    }
    // ---- mask (boundary chunks only; wave-uniform branch) ----
    if (kc + 63 > qw + 16) {
      int qv = qw + col + 16;
#pragma unroll
      for (int mbk = 0; mbk < 4; mbk++)
#pragma unroll
        for (int r = 0; r < 4; r++)
          if (kc + mbk * 16 + quad * 4 + r > qv) St[mbk][r] = -1e30f;
    }
    // ---- online softmax: in-lane 16 + shfl_xor(16,32) ----
    float cm0 = fmaxf(fmaxf(St[0][0], St[0][1]), fmaxf(St[0][2], St[0][3]));
    float cm1 = fmaxf(fmaxf(St[1][0], St[1][1]), fmaxf(St[1][2], St[1][3]));
    float cm2 = fmaxf(fmaxf(St[2][0], St[2][1]), fmaxf(St[2][2], St[2][3]));
    float cm3 = fmaxf(fmaxf(St[3][0], St[3][1]), fmaxf(St[3][2], St[3][3]));
    float cmax = fmaxf(fmaxf(cm0, cm1), fmaxf(cm2, cm3));
    cmax = fmaxf(cmax, __shfl_xor(cmax, 16));
    cmax = fmaxf(cmax, __shfl_xor(cmax, 32));
    float mn = fmaxf(m, cmax);
    float al = __expf(m - mn);
    m = mn;
    float ps = 0.f;
#pragma unroll
    for (int mbk = 0; mbk < 4; mbk++)
#pragma unroll
      for (int r = 0; r < 4; r++) {
        float p = __expf(St[mbk][r] - mn);
        ps += p;
        St[mbk][r] = p;
      }
    ps += __shfl_xor(ps, 16);
    ps += __shfl_xor(ps, 32);
    l = l * al + ps;
    // pack P (positive, finite) into PV B-frags via perm (round half-up)
    int4v pi[2];
#pragma unroll
    for (int pr = 0; pr < 2; pr++)
#pragma unroll
      for (int d = 0; d < 4; d++)
        pi[pr][d] = pack_bf16_pair(St[2 * pr + (d >> 1)][(d & 1) * 2 + 1],
                                   St[2 * pr + (d >> 1)][(d & 1) * 2]);
#pragma unroll
    for (int cb = 0; cb < 4; cb++)
#pragma unroll
      for (int r = 0; r < 4; r++) O[cb][r] *= al;
    // ---- O^T += V^T @ P ----
#pragma unroll
    for (int ks = 0; ks < 2; ks++) {
      bf16x8 prs = *(bf16x8*)&pi[ks];
#pragma unroll
      for (int cb = 0; cb < 4; cb++) {
        bf16x8 vf = *(const bf16x8*)(vbase + (size_t)cb * 16 * 1152 + kc + ks * 32);
        O[cb] = __builtin_amdgcn_mfma_f32_16x16x32_bf16(vf, prs, O[cb], 0, 0, 0);
      }
    }
  }

  // ---- split-K merge ----
  if (wave != 0) {
    Ms[wave - 1][lane] = m;
    Ls[wave - 1][lane] = l;
#pragma unroll
    for (int cb = 0; cb < 4; cb++)
#pragma unroll
      for (int r = 0; r < 4; r++) Os[wave - 1][cb * 4 + r][lane] = O[cb][r];
  }
  __syncthreads();
  if (wave == 0) {
    float m1 = Ms[0][lane], m2 = Ms[1][lane], m3 = Ms[2][lane];
    float mm = fmaxf(fmaxf(m, m1), fmaxf(m2, m3));
    float a0 = __expf(m - mm),  a1 = __expf(m1 - mm);
    float a2 = __expf(m2 - mm), a3 = __expf(m3 - mm);
    float ll = l * a0 + Ls[0][lane] * a1 + Ls[1][lane] * a2 + Ls[2][lane] * a3;
    float inv = 1.f / ll;
    short* zrow = (short*)Zb + ((size_t)(b * 1024 + qw + col)) * 2048 + hq * 64 + quad * 4;
#pragma unroll
    for (int cb = 0; cb < 4; cb++) {
      short4v s4;
#pragma unroll
      for (int r = 0; r < 4; r++) {
        float o = O[cb][r] * a0 + Os[0][cb * 4 + r][lane] * a1 +
                  Os[1][cb * 4 + r][lane] * a2 + Os[2][cb * 4 + r][lane] * a3;
        s4[r] = rnd_bf16(o * inv);
      }
      *(short4v*)(zrow + cb * 16) = s4;
    }
  }
}

// ---- GEMM2: 64x64 tiles, f32 out: out = Zb @ Wot^T ------------------------
__global__ __launch_bounds__(256) void gemm2_small(
    const bf16* __restrict__ A, const bf16* __restrict__ Bt, float* __restrict__ C,
    int K, int ldc) {
  __shared__ __align__(16) short As[64 * 32];
  __shared__ __align__(16) short Bs[64 * 32];
  const int tileM = blockIdx.y * 64, tileN = blockIdx.x * 64;
  const int tid = threadIdx.x, wave = tid >> 6, lane = tid & 63;
  const int wm = (wave >> 1) * 32, wn = (wave & 1) * 32;
  const int mrow = lane & 15, kq = lane >> 4;
  f32x4 acc[2][2] = {};

  for (int k0 = 0; k0 < K; k0 += 32) {
    {
      int c = wave * 64 + lane;
      int row = c >> 2, ko = (c & 3) * 8;
      const short* ga = (const short*)A + (size_t)(tileM + row) * K + k0 + ko;
      __builtin_amdgcn_global_load_lds(AS1(ga), AS3(&As[wave * 512]), 16, 0, 0);
    }
    {
      int c = wave * 64 + lane;
      int row = c >> 2, ko = (c & 3) * 8;
      const short* gb = (const short*)Bt + (size_t)(tileN + row) * K + k0 + ko;
      __builtin_amdgcn_global_load_lds(AS1(gb), AS3(&Bs[wave * 512]), 16, 0, 0);
    }
    __syncthreads();
    bf16x8 af[2], bfr[2];
#pragma unroll
    for (int t = 0; t < 2; t++) {
      af[t]  = *(const bf16x8*)&As[(wm + t * 16 + mrow) * 32 + kq * 8];
      bfr[t] = *(const bf16x8*)&Bs[(wn + t * 16 + mrow) * 32 + kq * 8];
    }
#pragma unroll
    for (int i = 0; i < 2; i++)
#pragma unroll
      for (int j = 0; j < 2; j++)
        acc[i][j] = __builtin_amdgcn_mfma_f32_16x16x32_bf16(af[i], bfr[j], acc[i][j], 0, 0, 0);
    __syncthreads();
  }
  const int col = lane & 15, rq = lane >> 4;
#pragma unroll
  for (int i = 0; i < 2; i++)
#pragma unroll
    for (int j = 0; j < 2; j++)
#pragma unroll
      for (int r = 0; r < 4; r++) {
        int mm = tileM + wm + i * 16 + rq * 4 + r;
        int nn = tileN + wn + j * 16 + col;
        C[(size_t)mm * ldc + nn] = acc[i][j][r];
      }
}

// ---------------------------------------------------------------------------
extern "C" void kernel_launch(void* const* d_in, const int* in_sizes, int n_in,
                              void* d_out, int out_size, void* d_ws, size_t ws_size,
                              hipStream_t stream) {
  const float* resid = (const float*)d_in[0];
  const float* WQ = (const float*)d_in[1];
  const float* WK = (const float*)d_in[2];
  const float* WV = (const float*)d_in[3];
  const float* WO = (const float*)d_in[4];
  const float* bQ = (const float*)d_in[5];
  const float* bK = (const float*)d_in[6];
  const float* bV = (const float*)d_in[7];
  const float* vk = (const float*)d_in[8];
  const float* vv = (const float*)d_in[9];
  float* out = (float*)d_out;

  // workspace layout, no aliasing (~41.5 MB):
  char* ws = (char*)d_ws;
  bf16* A_bf = (bf16*)(ws);                 // 4 MB   [2048][1024]
  bf16* Wt   = (bf16*)(ws + 4194304);       // 8 MB   [4096][1024]
  bf16* Wot  = (bf16*)(ws + 12582912);      // 4 MB   [1024][2048]
  bf16* Qb   = (bf16*)(ws + 16777216);      // 4 MB   [(b,h)][1024][32] scaled
  bf16* Kb   = (bf16*)(ws + 20971520);      // 4.5 MB [(b,h)][1152][32]
  bf16* Vb   = (bf16*)(ws + 25690112);      // 9 MB   [(b,h)][64][1152] permuted
  bf16* Zb   = (bf16*)(ws + 35127296);      // 8 MB   [2048][2048]

  prep<<<8704, 256, 0, stream>>>(resid, WV, WQ, WK, WO, vk, vv, A_bf, Wt, Wot, Kb, Vb);
  // QKV projection + fused rotary/bias/transpose epilogue (128x128 tiles)
  gemm1_fused<<<dim3(32, 16), 256, 0, stream>>>(A_bf, Wt, bQ, bK, bV, Qb, Kb, Vb);
  attn_mfma<<<4096, 256, 0, stream>>>(Qb, Kb, Vb, Zb);
  // out = Zb @ Wot^T : M=2048, N=1024, K=2048
  gemm2_small<<<dim3(16, 32), 256, 0, stream>>>(Zb, Wot, out, 2048, 1024);
}

// Round 7
// 179.341 us; speedup vs baseline: 1.0873x; 1.0873x over previous
//
#include <hip/hip_runtime.h>
#include <hip/hip_bf16.h>
#include <math.h>

// ---------------------------------------------------------------------------
// LowRankSparseAttention on MI355X (gfx950)
//   1. prep: cvt resid->A_bf, cvt W_V->Wt rows 2048+, virtual K/V fills,
//      transpose W_Q/W_K->Wt, transpose W_O->Wot
//   2. gemm1_fused (128x128): QKV proj, fused epilogue:
//        Q: +bQ, rotary, /sqrt(32) -> Qb bf16 [(b,h)][1024][32]
//        K: +bK, rotary            -> Kb bf16 [(b,h)][1152][32]
//        V: +bV -> Vb bf16 [(b,h)][17 chunks][8KB], token-permuted within
//           32-groups AND XOR-swizzled 16B units: slot = ch*8 + (q ^ (ch&7))
//   3. attn_mfma: per-wave flash attn (S^T/O^T, P in regs); V chunk staged
//      to LDS via contiguous global_load_lds (kills the scattered-16B
//      request storm), software-pipelined K/V prefetch -> Zb bf16
//   4. gemm2 (64x64 tiles): out[2048x1024] f32 = Zb @ Wot^T
// ---------------------------------------------------------------------------

typedef short bf16x8 __attribute__((ext_vector_type(8)));
typedef short short4v __attribute__((ext_vector_type(4)));
typedef float f32x4 __attribute__((ext_vector_type(4)));
typedef int int4v __attribute__((ext_vector_type(4)));
typedef __hip_bfloat16 bf16;

#define AS1(p) ((const __attribute__((address_space(1))) void*)(const void*)(p))
#define AS3(p) ((__attribute__((address_space(3))) void*)(void*)(p))

static constexpr float INV_SCALE = 0.17677669529663687f;  // 1/sqrt(32)

// fast RNE f32->bf16 (finite values only): 4 int ops
__device__ inline short rnd_bf16(float x) {
  unsigned u = __float_as_uint(x);
  return (short)((u + 0x7fffu + ((u >> 16) & 1u)) >> 16);
}

// pack two positive f32 -> dword of bf16 pair (round half-up)
__device__ inline int pack_bf16_pair(float hi, float lo) {
  unsigned a = __float_as_uint(hi) + 0x8000u;
  unsigned b = __float_as_uint(lo) + 0x8000u;
  return (int)__builtin_amdgcn_perm(a, b, 0x07060302u);
}

// ---- merged preprocessing kernel ------------------------------------------
__global__ __launch_bounds__(256) void prep(
    const float* __restrict__ resid, const float* __restrict__ WV,
    const float* __restrict__ WQ, const float* __restrict__ WK,
    const float* __restrict__ WO, const float* __restrict__ vk,
    const float* __restrict__ vv,
    bf16* __restrict__ A_bf, bf16* __restrict__ Wt, bf16* __restrict__ Wot,
    bf16* __restrict__ Kb, bf16* __restrict__ Vb) {
  __shared__ float t[64][65];
  const int blk = blockIdx.x, tid = threadIdx.x;
  if (blk < 4096) {
    const float* src = (blk < 2048) ? resid : WV;
    short* dst = (short*)((blk < 2048) ? A_bf : (Wt + (size_t)2048 * 1024));
    int i = ((blk & 2047) * 256 + tid) * 4;
    float4 v = *(const float4*)(src + i);
    dst[i + 0] = rnd_bf16(v.x); dst[i + 1] = rnd_bf16(v.y);
    dst[i + 2] = rnd_bf16(v.z); dst[i + 3] = rnd_bf16(v.w);
  } else if (blk < 7168) {
    int idx = (blk - 4096) * 256 + tid;
    if (idx < 262144) {              // Kb virtual: toks 1024..1151 per (b,h)
      int b = idx >> 17, rem = idx & 131071;
      int j = rem >> 10, c = rem & 1023;     // c = h*32+d
      int h = c >> 5, d = c & 31;
      float v = (j < 16) ? vk[j * 1024 + c] : 0.f;
      Kb[(((size_t)(b * 32 + h)) * 1152 + 1024 + j) * 32 + d] = __float2bfloat16(v);
    } else if (idx < 524288) {       // Vb virtual: chunk 16 (toks 1024..1087)
      int i2 = idx - 262144;         // [0, 262144): 2 b x 2048 ch x 64 p
      int b = i2 >> 17, rem = i2 & 131071;
      int ch = rem >> 6, p = rem & 63;
      int pl = p & 31;
      int u = (p & 32) | ((pl & 4) << 2) | ((pl & 24) >> 1) | (pl & 3);
      float v = (u < 16) ? vv[(size_t)u * 2048 + ch] : 0.f;
      int hv = ch >> 6, c = ch & 63;
      int slot = c * 8 + ((p >> 3) ^ (c & 7));
      Vb[((((size_t)(b * 32 + hv)) * 17 + 16) * 512 + slot) * 8 + (p & 7)] = __float2bfloat16(v);
    }
  } else if (blk < 8192) {
    int i = blk - 7168;
    int mt = i & 15, h = (i >> 4) & 31, qk = i >> 9;
    const float* W = qk ? WK : WQ;
    const int m0 = mt * 64;
    for (int idx = tid; idx < 64 * 32; idx += 256) {
      int ii = idx >> 5, d = idx & 31;
      t[ii][d] = W[((size_t)h * 1024 + m0 + ii) * 32 + d];
    }
    __syncthreads();
    const int rowbase = qk * 1024 + h * 32;
    for (int idx = tid; idx < 32 * 64; idx += 256) {
      int d = idx >> 6, ii = idx & 63;
      Wt[(size_t)(rowbase + d) * 1024 + m0 + ii] = __float2bfloat16(t[ii][d]);
    }
  } else {
    int i = blk - 8192;
    int h0 = (i & 31) * 64, m0 = (i >> 5) * 64;
    for (int idx = tid; idx < 64 * 64; idx += 256) {
      int ii = idx >> 6, j = idx & 63;
      t[ii][j] = WO[(size_t)(h0 + ii) * 1024 + m0 + j];
    }
    __syncthreads();
    for (int idx = tid; idx < 64 * 64; idx += 256) {
      int ii = idx >> 6, j = idx & 63;
      Wot[(size_t)(m0 + ii) * 2048 + h0 + j] = __float2bfloat16(t[j][ii]);
    }
  }
}

// ---- GEMM1 + fused epilogue: 128(M) x 128(N) tiles, K=1024 ----------------
__global__ __launch_bounds__(256) void gemm1_fused(
    const bf16* __restrict__ A, const bf16* __restrict__ Bt,
    const float* __restrict__ bQ, const float* __restrict__ bK,
    const float* __restrict__ bV,
    bf16* __restrict__ Qb, bf16* __restrict__ Kb, bf16* __restrict__ Vb) {
  __shared__ __align__(16) short As[128 * 32];
  __shared__ __align__(16) short Bs[128 * 32];
  const int tileM = blockIdx.y * 128, tileN = blockIdx.x * 128;
  const int tid = threadIdx.x, wave = tid >> 6, lane = tid & 63;
  const int wm = (wave >> 1) * 64, wn = (wave & 1) * 64;
  const int mrow = lane & 15, kq = lane >> 4;
  f32x4 acc[4][4] = {};

  for (int k0 = 0; k0 < 1024; k0 += 32) {
#pragma unroll
    for (int i = 0; i < 2; i++) {
      int c = (wave * 2 + i) * 64 + lane;
      int row = c >> 2, ko = (c & 3) * 8;
      const short* ga = (const short*)A + (size_t)(tileM + row) * 1024 + k0 + ko;
      const short* gb = (const short*)Bt + (size_t)(tileN + row) * 1024 + k0 + ko;
      __builtin_amdgcn_global_load_lds(AS1(ga), AS3(&As[(wave * 2 + i) * 512]), 16, 0, 0);
      __builtin_amdgcn_global_load_lds(AS1(gb), AS3(&Bs[(wave * 2 + i) * 512]), 16, 0, 0);
    }
    __syncthreads();
    bf16x8 af[4], bfr[4];
#pragma unroll
    for (int t = 0; t < 4; t++) {
      af[t]  = *(const bf16x8*)&As[(wm + t * 16 + mrow) * 32 + kq * 8];
      bfr[t] = *(const bf16x8*)&Bs[(wn + t * 16 + mrow) * 32 + kq * 8];
    }
#pragma unroll
    for (int i = 0; i < 4; i++)
#pragma unroll
      for (int j = 0; j < 4; j++)
        acc[i][j] = __builtin_amdgcn_mfma_f32_16x16x32_bf16(af[i], bfr[j], acc[i][j], 0, 0, 0);
    __syncthreads();
  }

  const int col = lane & 15, rq = lane >> 4;
  if (tileN < 2048) {
    // ---- two QK heads per wave: bias + rotary (d = col) -------------------
    const int qk = tileN >> 10;
    const float* bias = qk ? bK : bQ;
    const int hA = ((tileN & 1023) + wn) >> 5;
    const float b0a = bias[hA * 32 + col],        b1a = bias[hA * 32 + col + 16];
    const float b0b = bias[(hA + 1) * 32 + col],  b1b = bias[(hA + 1) * 32 + col + 16];
    const float invf = exp2f(col * -0.8304820237218406f);  // -log2(10000)/16
#pragma unroll
    for (int i = 0; i < 4; i++)
#pragma unroll
      for (int r = 0; r < 4; r++) {
        int mg = tileM + wm + i * 16 + rq * 4 + r;
        int s = mg & 1023, bb = mg >> 10;
        float sv, cv;
        __sincosf((float)s * invf, &sv, &cv);
#pragma unroll
        for (int p = 0; p < 2; p++) {
          float x0 = acc[i][2 * p][r]     + (p ? b0b : b0a);
          float x1 = acc[i][2 * p + 1][r] + (p ? b1b : b1a);
          float y0 = x0 * cv - x1 * sv, y1 = x1 * cv + x0 * sv;
          int h = hA + p;
          if (qk == 0) {
            short* q = (short*)Qb + (((size_t)(bb * 32 + h)) * 1024 + s) * 32 + col;
            q[0]  = rnd_bf16(y0 * INV_SCALE);
            q[16] = rnd_bf16(y1 * INV_SCALE);
          } else {
            short* kp = (short*)Kb + (((size_t)(bb * 32 + h)) * 1152 + s) * 32 + col;
            kp[0]  = rnd_bf16(y0);
            kp[16] = rnd_bf16(y1);
          }
        }
      }
  } else {
    // ---- V head: bias + permuted+swizzled store into chunked Vb -----------
    const int hv = (tileN - 2048 + wn) >> 6;
#pragma unroll
    for (int i = 0; i < 4; i++)
#pragma unroll
      for (int j = 0; j < 4; j++) {
        int c = j * 16 + col;
        float bias = bV[hv * 64 + c];
        int m0 = tileM + wm + i * 16 + rq * 4;
        int s0 = m0 & 1023, bb = m0 >> 10;
        int chunk = s0 >> 6, w = s0 & 63, u0 = w & 31;
        int p0 = (u0 & 3) | ((u0 & 16) >> 2) | ((u0 & 8) << 1) | ((u0 & 4) << 1);
        int p = (w & 32) | p0;                 // 4-aligned
        int slot = c * 8 + ((p >> 3) ^ (c & 7));
        short4v s4;
#pragma unroll
        for (int r = 0; r < 4; r++) s4[r] = rnd_bf16(acc[i][j][r] + bias);
        *(short4v*)((short*)Vb +
            ((((size_t)(bb * 32 + hv)) * 17 + chunk) * 512 + slot) * 8 + (p & 7)) = s4;
      }
  }
}

// ---- MFMA flash attention: LDS-staged V, software-pipelined ---------------
// Wave = 16 queries (mirrored tile map). S^T = K@Q^T (lane owns query col;
// 2-shfl softmax reduce); packed S^T regs ARE the PV B-frag. V chunk (8KB,
// swizzled) staged via 8 contiguous global_load_lds; frags read from LDS
// 2-way-conflict-free. Pipeline: K(ci+1) then V(ci+1) issued after ds_reads
// (in-order vmcnt => QK waits vmcnt(8), staging stays in flight).
__global__ __launch_bounds__(256) void attn_mfma(
    const bf16* __restrict__ Qb, const bf16* __restrict__ Kb,
    const bf16* __restrict__ Vb, bf16* __restrict__ Zb) {
  __shared__ __align__(16) short Vs[4][4096];
  const int flat = blockIdx.x;
  const int xcd = flat & 7, jj = flat >> 3;
  const int hqb = xcd * 8 + (jj & 7);
  const int x = jj >> 3;                    // 0..15
  const int hq = hqb & 31, b = hqb >> 5;
  const int wave = threadIdx.x >> 6, lane = threadIdx.x & 63;
  const int col = lane & 15, quad = lane >> 4;
  const int t = (wave == 0) ? x : (wave == 1) ? 31 - x : (wave == 2) ? 32 + x : 63 - x;
  const int qw = t * 16;

  const bf16x8 qf = *(const bf16x8*)((const short*)Qb +
      (((size_t)(b * 32 + hq)) * 1024 + qw + col) * 32 + quad * 8);
  const short* kbase = (const short*)Kb + ((size_t)(b * 32 + hq)) * 1152 * 32 + quad * 8;
  const short* vbh = (const short*)Vb + ((size_t)(b * 32 + hq)) * (17 * 4096) + lane * 8;
  short* vdst = &Vs[wave][0];

  const int kend = (qw + 32 < 1040) ? qw + 32 : 1040;
  const int nch = (kend + 63) >> 6;

  f32x4 O[4] = {};
  float m = -1e30f, l = 0.f;

  // prologue: K(0) first (older in vmcnt FIFO), then V(0) staging
  bf16x8 kf[4];
#pragma unroll
  for (int mbk = 0; mbk < 4; mbk++)
    kf[mbk] = *(const bf16x8*)(kbase + (size_t)(mbk * 16 + col) * 32);
#pragma unroll
  for (int g = 0; g < 8; g++)
    __builtin_amdgcn_global_load_lds(AS1(vbh + g * 512), AS3(vdst + g * 512), 16, 0, 0);

  for (int ci = 0; ci < nch; ci++) {
    const int kc = ci * 64;
    // ---- S^T = K @ Q^T ----
    f32x4 St[4] = {};
#pragma unroll
    for (int mbk = 0; mbk < 4; mbk++)
      St[mbk] = __builtin_amdgcn_mfma_f32_16x16x32_bf16(kf[mbk], qf, St[mbk], 0, 0, 0);
    // ---- mask (boundary chunks only) ----
    if (kc + 63 > qw + 16) {
      int qv = qw + col + 16;
#pragma unroll
      for (int mbk = 0; mbk < 4; mbk++)
#pragma unroll
        for (int r = 0; r < 4; r++)
          if (kc + mbk * 16 + quad * 4 + r > qv) St[mbk][r] = -1e30f;
    }
    // ---- online softmax ----
    float cm0 = fmaxf(fmaxf(St[0][0], St[0][1]), fmaxf(St[0][2], St[0][3]));
    float cm1 = fmaxf(fmaxf(St[1][0], St[1][1]), fmaxf(St[1][2], St[1][3]));
    float cm2 = fmaxf(fmaxf(St[2][0], St[2][1]), fmaxf(St[2][2], St[2][3]));
    float cm3 = fmaxf(fmaxf(St[3][0], St[3][1]), fmaxf(St[3][2], St[3][3]));
    float cmax = fmaxf(fmaxf(cm0, cm1), fmaxf(cm2, cm3));
    cmax = fmaxf(cmax, __shfl_xor(cmax, 16));
    cmax = fmaxf(cmax, __shfl_xor(cmax, 32));
    float mn = fmaxf(m, cmax);
    float al = __expf(m - mn);
    m = mn;
    float ps = 0.f;
#pragma unroll
    for (int mbk = 0; mbk < 4; mbk++)
#pragma unroll
      for (int r = 0; r < 4; r++) {
        float p = __expf(St[mbk][r] - mn);
        ps += p;
        St[mbk][r] = p;
      }
    ps += __shfl_xor(ps, 16);
    ps += __shfl_xor(ps, 32);
    l = l * al + ps;
    int4v pi[2];
#pragma unroll
    for (int pr = 0; pr < 2; pr++)
#pragma unroll
      for (int d = 0; d < 4; d++)
        pi[pr][d] = pack_bf16_pair(St[2 * pr + (d >> 1)][(d & 1) * 2 + 1],
                                   St[2 * pr + (d >> 1)][(d & 1) * 2]);
#pragma unroll
    for (int cb = 0; cb < 4; cb++)
#pragma unroll
      for (int r = 0; r < 4; r++) O[cb][r] *= al;
    // ---- V(ci) LDS ready; read frags ----
    asm volatile("s_waitcnt vmcnt(0)" ::: "memory");
    bf16x8 vf[2][4];
#pragma unroll
    for (int ks = 0; ks < 2; ks++)
#pragma unroll
      for (int cb = 0; cb < 4; cb++) {
        int slot = (cb * 16 + col) * 8 + ((ks * 4 + quad) ^ (col & 7));
        vf[ks][cb] = *(const bf16x8*)(vdst + slot * 8);
      }
    asm volatile("s_waitcnt lgkmcnt(0)" ::: "memory");   // WAR guard vs restage
    // ---- prefetch K(ci+1) then stage V(ci+1) ----
    if (ci + 1 < nch) {
      const int kn = kc + 64;
#pragma unroll
      for (int mbk = 0; mbk < 4; mbk++)
        kf[mbk] = *(const bf16x8*)(kbase + (size_t)(kn + mbk * 16 + col) * 32);
      const short* vsrc = vbh + (ci + 1) * 4096;
#pragma unroll
      for (int g = 0; g < 8; g++)
        __builtin_amdgcn_global_load_lds(AS1(vsrc + g * 512), AS3(vdst + g * 512), 16, 0, 0);
    }
    // ---- O^T += V^T @ P ----
#pragma unroll
    for (int ks = 0; ks < 2; ks++) {
      bf16x8 prs = *(bf16x8*)&pi[ks];
#pragma unroll
      for (int cb = 0; cb < 4; cb++)
        O[cb] = __builtin_amdgcn_mfma_f32_16x16x32_bf16(vf[ks][cb], prs, O[cb], 0, 0, 0);
    }
  }
  // ---- epilogue ----
  float inv = 1.f / l;
  short* zrow = (short*)Zb + ((size_t)(b * 1024 + qw + col)) * 2048 + hq * 64 + quad * 4;
#pragma unroll
  for (int cb = 0; cb < 4; cb++) {
    short4v s4;
#pragma unroll
    for (int r = 0; r < 4; r++) s4[r] = rnd_bf16(O[cb][r] * inv);
    *(short4v*)(zrow + cb * 16) = s4;
  }
}

// ---- GEMM2: 64x64 tiles, f32 out: out = Zb @ Wot^T ------------------------
__global__ __launch_bounds__(256) void gemm2_small(
    const bf16* __restrict__ A, const bf16* __restrict__ Bt, float* __restrict__ C,
    int K, int ldc) {
  __shared__ __align__(16) short As[64 * 32];
  __shared__ __align__(16) short Bs[64 * 32];
  const int tileM = blockIdx.y * 64, tileN = blockIdx.x * 64;
  const int tid = threadIdx.x, wave = tid >> 6, lane = tid & 63;
  const int wm = (wave >> 1) * 32, wn = (wave & 1) * 32;
  const int mrow = lane & 15, kq = lane >> 4;
  f32x4 acc[2][2] = {};

  for (int k0 = 0; k0 < K; k0 += 32) {
    {
      int c = wave * 64 + lane;
      int row = c >> 2, ko = (c & 3) * 8;
      const short* ga = (const short*)A + (size_t)(tileM + row) * K + k0 + ko;
      __builtin_amdgcn_global_load_lds(AS1(ga), AS3(&As[wave * 512]), 16, 0, 0);
    }
    {
      int c = wave * 64 + lane;
      int row = c >> 2, ko = (c & 3) * 8;
      const short* gb = (const short*)Bt + (size_t)(tileN + row) * K + k0 + ko;
      __builtin_amdgcn_global_load_lds(AS1(gb), AS3(&Bs[wave * 512]), 16, 0, 0);
    }
    __syncthreads();
    bf16x8 af[2], bfr[2];
#pragma unroll
    for (int t = 0; t < 2; t++) {
      af[t]  = *(const bf16x8*)&As[(wm + t * 16 + mrow) * 32 + kq * 8];
      bfr[t] = *(const bf16x8*)&Bs[(wn + t * 16 + mrow) * 32 + kq * 8];
    }
#pragma unroll
    for (int i = 0; i < 2; i++)
#pragma unroll
      for (int j = 0; j < 2; j++)
        acc[i][j] = __builtin_amdgcn_mfma_f32_16x16x32_bf16(af[i], bfr[j], acc[i][j], 0, 0, 0);
    __syncthreads();
  }
  const int col = lane & 15, rq = lane >> 4;
#pragma unroll
  for (int i = 0; i < 2; i++)
#pragma unroll
    for (int j = 0; j < 2; j++)
#pragma unroll
      for (int r = 0; r < 4; r++) {
        int mm = tileM + wm + i * 16 + rq * 4 + r;
        int nn = tileN + wn + j * 16 + col;
        C[(size_t)mm * ldc + nn] = acc[i][j][r];
      }
}

// ---------------------------------------------------------------------------
extern "C" void kernel_launch(void* const* d_in, const int* in_sizes, int n_in,
                              void* d_out, int out_size, void* d_ws, size_t ws_size,
                              hipStream_t stream) {
  const float* resid = (const float*)d_in[0];
  const float* WQ = (const float*)d_in[1];
  const float* WK = (const float*)d_in[2];
  const float* WV = (const float*)d_in[3];
  const float* WO = (const float*)d_in[4];
  const float* bQ = (const float*)d_in[5];
  const float* bK = (const float*)d_in[6];
  const float* bV = (const float*)d_in[7];
  const float* vk = (const float*)d_in[8];
  const float* vv = (const float*)d_in[9];
  float* out = (float*)d_out;

  // workspace layout, no aliasing (~41.5 MB):
  char* ws = (char*)d_ws;
  bf16* A_bf = (bf16*)(ws);                 // 4 MB   [2048][1024]
  bf16* Wt   = (bf16*)(ws + 4194304);       // 8 MB   [4096][1024]
  bf16* Wot  = (bf16*)(ws + 12582912);      // 4 MB   [1024][2048]
  bf16* Qb   = (bf16*)(ws + 16777216);      // 4 MB   [(b,h)][1024][32] scaled
  bf16* Kb   = (bf16*)(ws + 20971520);      // 4.5 MB [(b,h)][1152][32]
  bf16* Vb   = (bf16*)(ws + 25690112);      // 8.5 MB [(b,h)][17][512 slots][8]
  bf16* Zb   = (bf16*)(ws + 35127296);      // 8 MB   [2048][2048]

  prep<<<8704, 256, 0, stream>>>(resid, WV, WQ, WK, WO, vk, vv, A_bf, Wt, Wot, Kb, Vb);
  // QKV projection + fused rotary/bias/transpose epilogue (128x128 tiles)
  gemm1_fused<<<dim3(32, 16), 256, 0, stream>>>(A_bf, Wt, bQ, bK, bV, Qb, Kb, Vb);
  attn_mfma<<<1024, 256, 0, stream>>>(Qb, Kb, Vb, Zb);
  // out = Zb @ Wot^T : M=2048, N=1024, K=2048
  gemm2_small<<<dim3(16, 32), 256, 0, stream>>>(Zb, Wot, out, 2048, 1024);
}